// Round 5
// baseline (44.712 us; speedup 1.0000x reference)
//
#include <hip/hip_runtime.h>
#include <hip/hip_bf16.h>
#include <math.h>

// Problem constants (fixed by reference): N=2000 nodes, B=2000 bills, D=32, K=3.
#define NN  2000
#define NB  2000
#define DD  32
#define NP  8        // politicians per block (uniform inner loop)
#define TPB 256      // bills per block, one per thread
#define SD  (DD + 1) // LDS row stride 33 -> conflict-free row reads

// Lanes = bills. Per block: zb tile staged LDS->pinned VGPRs (once),
// zp tile (3 rows x NP pols = 3KB) staged in LDS (read as uniform-address
// ds_read_b128 broadcasts in the j-loop -> no per-j global latency),
// all NP events words prefetched upfront (one HBM latency per wave, not 8).
__global__ __launch_bounds__(TPB, 3) void pol2vec_kernel(
    const int*   __restrict__ events,   // [N,B] 0/1
    const float* __restrict__ tarr,     // [B]
    const float* __restrict__ beta,     // [B]
    const float* __restrict__ gamma,    // [N]
    const float* __restrict__ zb,       // [B,D]
    const float* __restrict__ zp,       // [K,N,D]
    float*       __restrict__ out)      // [1]
{
    __shared__ float s_zb[TPB][SD];                    // 33.8 KB
    __shared__ alignas(16) float s_zp[3 * NP * DD];    // 3 KB
    __shared__ float s_red[TPB / 64];

    const int tid = threadIdx.x;
    const int b0  = blockIdx.x * TPB;
    const int b   = b0 + tid;                 // this thread's bill
    const int n0  = blockIdx.y * NP;          // block's politician range
    const bool valid = (b < NB);
    const int bc  = valid ? b : 0;            // clamped (contribution masked)

    // ---- Stage zp tile: 3*NP*DD floats, coalesced ----
    for (int u = tid; u < 3 * NP * DD; u += TPB) {
        const int k   = u / (NP * DD);
        const int rem = u - k * (NP * DD);
        const int nl  = rem / DD;
        const int d   = rem - nl * DD;
        s_zp[u] = zp[((size_t)k * NN + n0 + nl) * DD + d];
    }

    // ---- Stage zb tile: coalesced global -> LDS (stride-33) ----
#pragma unroll
    for (int u0 = 0; u0 < TPB * DD / 4; u0 += TPB) {
        const int u   = u0 + tid;
        const int row = (4 * u) / DD;
        const int col = (4 * u) % DD;
        int gr = b0 + row;                    // clamp OOB rows (x=7 tail)
        gr = gr < NB ? gr : NB - 1;
        const float4 v = *(const float4*)(zb + (size_t)gr * DD + col);
        s_zb[row][col + 0] = v.x;
        s_zb[row][col + 1] = v.y;
        s_zb[row][col + 2] = v.z;
        s_zb[row][col + 3] = v.w;
    }

    // ---- Prefetch all NP event words (independent loads, 1 latency) ----
    float sgn[NP];
#pragma unroll
    for (int j = 0; j < NP; ++j) {
        sgn[j] = (events[(size_t)(n0 + j) * NB + bc] != 0) ? 1.f : -1.f;
    }
    float gam[NP];
#pragma unroll
    for (int j = 0; j < NP; ++j) gam[j] = gamma[n0 + j];   // uniform

    __syncthreads();

    // Own bill row: LDS -> VGPRs, pinned so it can't be rematerialized.
    float zr[DD];
#pragma unroll
    for (int d = 0; d < DD; ++d) zr[d] = s_zb[tid][d];     // (tid+d)%32 banks
#pragma unroll
    for (int d = 0; d < DD; ++d) asm volatile("" : "+v"(zr[d]));

    const float t   = tarr[bc];
    const float bb  = beta[bc];
    const float t2h = 0.5f * t * t;           // t^2 / 2!

    float acc = 0.f;

#pragma unroll 2
    for (int j = 0; j < NP; ++j) {
        const float4* pA = (const float4*)&s_zp[(0 * NP + j) * DD];
        const float4* pB = (const float4*)&s_zp[(1 * NP + j) * DD];
        const float4* pC = (const float4*)&s_zp[(2 * NP + j) * DD];

        float d2a = 0.f, d2b = 0.f, d2c = 0.f, d2d = 0.f;
#pragma unroll
        for (int i = 0; i < DD / 4; ++i) {
            const float4 a  = pA[i];          // ds_read_b128, uniform addr
            const float4 bv = pB[i];
            const float4 cv = pC[i];
            // pos = A + t*B + (t^2/2)*C
            float p0 = fmaf(t2h, cv.x, fmaf(t, bv.x, a.x));
            float p1 = fmaf(t2h, cv.y, fmaf(t, bv.y, a.y));
            float p2 = fmaf(t2h, cv.z, fmaf(t, bv.z, a.z));
            float p3 = fmaf(t2h, cv.w, fmaf(t, bv.w, a.w));
            float f0 = p0 - zr[4 * i + 0];
            float f1 = p1 - zr[4 * i + 1];
            float f2 = p2 - zr[4 * i + 2];
            float f3 = p3 - zr[4 * i + 3];
            d2a = fmaf(f0, f0, d2a);
            d2b = fmaf(f1, f1, d2b);
            d2c = fmaf(f2, f2, d2c);
            d2d = fmaf(f3, f3, d2d);
        }
        const float d2 = (d2a + d2b) + (d2c + d2d);
        const float L  = gam[j] + bb - sqrtf(d2);
        const float s  = sgn[j] * L;
        // -log_sigmoid(s) = max(-s,0) + log(1+exp(-|s|)); hw exp/log.
        acc += fmaxf(-s, 0.f) + __logf(1.f + __expf(-fabsf(s)));
    }

    if (!valid) acc = 0.f;

    // Wave64 shuffle reduction, then cross-wave via LDS, one atomic per block.
#pragma unroll
    for (int o = 32; o > 0; o >>= 1) acc += __shfl_down(acc, o, 64);
    const int wave = tid >> 6;
    const int lane = tid & 63;
    if (lane == 0) s_red[wave] = acc;
    __syncthreads();
    if (tid == 0) {
        float s = 0.f;
#pragma unroll
        for (int w = 0; w < TPB / 64; ++w) s += s_red[w];
        atomicAdd(out, s);
    }
}

extern "C" void kernel_launch(void* const* d_in, const int* in_sizes, int n_in,
                              void* d_out, int out_size, void* d_ws, size_t ws_size,
                              hipStream_t stream) {
    const int*   events = (const int*)d_in[0];    // [N,B]
    const float* tarr   = (const float*)d_in[1];  // [B]
    const float* beta   = (const float*)d_in[2];  // [B]
    const float* gamma  = (const float*)d_in[3];  // [N]
    const float* zb     = (const float*)d_in[4];  // [B,D]
    const float* zp     = (const float*)d_in[5];  // [K,N,D]
    float* out = (float*)d_out;

    // d_out is poisoned once (0xAA) and never re-poisoned between replays:
    // zero it ourselves every launch (graph-capture-safe async memset).
    hipMemsetAsync(out, 0, (size_t)out_size * sizeof(float), stream);

    dim3 grid((NB + TPB - 1) / TPB, NN / NP);
    pol2vec_kernel<<<grid, TPB, 0, stream>>>(events, tarr, beta, gamma, zb, zp, out);
}

// Round 6
// 35.439 us; speedup vs baseline: 1.2616x; 1.2616x over previous
//
#include <hip/hip_runtime.h>
#include <hip/hip_bf16.h>
#include <math.h>

// Problem constants (fixed by reference): N=2000 nodes, B=2000 bills, D=32, K=3.
#define NN    2000
#define NB    2000
#define DD    32
#define NP    16                    // politicians per block
#define TPB   64                    // one wave per block; bills = lanes
#define GX    ((NB + TPB - 1) / TPB)  // 32
#define GY    (NN / NP)               // 125
#define NPART (GX * GY)               // 4000 partial sums in d_ws

// Main kernel: lanes = bills (coalesced events/t/beta/zb), politicians =
// uniform unrolled loop (zp/gamma scalarize to s_load -> constant cache).
// No LDS, no atomics, no memset dependency: partial per block -> d_ws slot.
__global__ __launch_bounds__(TPB, 4) void pol2vec_main(
    const int*   __restrict__ events,   // [N,B] 0/1
    const float* __restrict__ tarr,     // [B]
    const float* __restrict__ beta,     // [B]
    const float* __restrict__ gamma,    // [N]
    const float* __restrict__ zb,       // [B,D]
    const float* __restrict__ zp,       // [K,N,D]
    float*       __restrict__ partials) // [NPART] in d_ws
{
    const int lane = threadIdx.x;
    const int b    = blockIdx.x * TPB + lane;
    const int n0   = blockIdx.y * NP;
    const bool valid = (b < NB);
    const int bc   = valid ? b : NB - 1;   // clamp; contribution masked later

    // Per-lane bill state (coalesced one-time loads).
    const float t   = tarr[bc];
    const float bb  = beta[bc];
    const float t2h = 0.5f * t * t;        // t^2 / 2!

    // Own zb row -> 32 VGPRs, pinned (anti-rematerialization, r3 pathology).
    float zr[DD];
    const float4* zb4 = (const float4*)(zb + (size_t)bc * DD);
#pragma unroll
    for (int i = 0; i < DD / 4; ++i) {
        const float4 v = zb4[i];
        zr[4 * i + 0] = v.x; zr[4 * i + 1] = v.y;
        zr[4 * i + 2] = v.z; zr[4 * i + 3] = v.w;
    }
#pragma unroll
    for (int d = 0; d < DD; ++d) asm volatile("" : "+v"(zr[d]));

    // Prefetch all NP event words (independent coalesced loads, one latency).
    int ev[NP];
#pragma unroll
    for (int j = 0; j < NP; ++j) ev[j] = events[(size_t)(n0 + j) * NB + bc];

    float acc = 0.f;

#pragma unroll 2
    for (int j = 0; j < NP; ++j) {
        const int n = n0 + j;
        const float g = gamma[n];                                  // uniform
        const float4* pA = (const float4*)(zp + (size_t)n * DD);   // uniform
        const float4* pB = (const float4*)(zp + ((size_t)NN + n) * DD);
        const float4* pC = (const float4*)(zp + ((size_t)2 * NN + n) * DD);

        float d2a = 0.f, d2b = 0.f, d2c = 0.f, d2d = 0.f;
#pragma unroll
        for (int i = 0; i < DD / 4; ++i) {
            const float4 a  = pA[i];
            const float4 bv = pB[i];
            const float4 cv = pC[i];
            // pos = A + t*B + (t^2/2)*C
            float p0 = fmaf(t2h, cv.x, fmaf(t, bv.x, a.x));
            float p1 = fmaf(t2h, cv.y, fmaf(t, bv.y, a.y));
            float p2 = fmaf(t2h, cv.z, fmaf(t, bv.z, a.z));
            float p3 = fmaf(t2h, cv.w, fmaf(t, bv.w, a.w));
            float f0 = p0 - zr[4 * i + 0];
            float f1 = p1 - zr[4 * i + 1];
            float f2 = p2 - zr[4 * i + 2];
            float f3 = p3 - zr[4 * i + 3];
            d2a = fmaf(f0, f0, d2a);
            d2b = fmaf(f1, f1, d2b);
            d2c = fmaf(f2, f2, d2c);
            d2d = fmaf(f3, f3, d2d);
        }
        const float d2 = (d2a + d2b) + (d2c + d2d);
        const float L  = g + bb - sqrtf(d2);
        const float s  = ev[j] ? L : -L;
        // -log_sigmoid(s) = max(-s,0) + log(1+exp(-|s|)); hw exp/log.
        acc += fmaxf(-s, 0.f) + __logf(1.f + __expf(-fabsf(s)));
    }

    if (!valid) acc = 0.f;

    // Single-wave block: shuffle reduce, lane 0 overwrites its partial slot.
#pragma unroll
    for (int o = 32; o > 0; o >>= 1) acc += __shfl_down(acc, o, 64);
    if (lane == 0) partials[blockIdx.y * GX + blockIdx.x] = acc;
}

// Tiny reducer: 4000 partials -> d_out[0] (overwrite; no pre-zero needed).
__global__ __launch_bounds__(256) void pol2vec_reduce(
    const float* __restrict__ partials, float* __restrict__ out)
{
    __shared__ float s_red[4];
    const int tid = threadIdx.x;
    float s = 0.f;
    for (int i = tid; i < NPART; i += 256) s += partials[i];
#pragma unroll
    for (int o = 32; o > 0; o >>= 1) s += __shfl_down(s, o, 64);
    if ((tid & 63) == 0) s_red[tid >> 6] = s;
    __syncthreads();
    if (tid == 0) out[0] = (s_red[0] + s_red[1]) + (s_red[2] + s_red[3]);
}

extern "C" void kernel_launch(void* const* d_in, const int* in_sizes, int n_in,
                              void* d_out, int out_size, void* d_ws, size_t ws_size,
                              hipStream_t stream) {
    const int*   events = (const int*)d_in[0];    // [N,B]
    const float* tarr   = (const float*)d_in[1];  // [B]
    const float* beta   = (const float*)d_in[2];  // [B]
    const float* gamma  = (const float*)d_in[3];  // [N]
    const float* zb     = (const float*)d_in[4];  // [B,D]
    const float* zp     = (const float*)d_in[5];  // [K,N,D]
    float* out      = (float*)d_out;
    float* partials = (float*)d_ws;   // overwritten every call: poison-proof

    dim3 grid(GX, GY);
    pol2vec_main<<<grid, TPB, 0, stream>>>(events, tarr, beta, gamma, zb, zp,
                                           partials);
    pol2vec_reduce<<<1, 256, 0, stream>>>(partials, out);
}